// Round 1
// baseline (210.962 us; speedup 1.0000x reference)
//
#include <hip/hip_runtime.h>

#define MAX_SEP 512
#define T_ROWS 1025          // 2*MAX_SEP+1
#define H 160
#define B 4
#define S 256
#define HV (H/4)             // 40 float4 per h-row

// ---------------------------------------------------------------------------
// Kernel A: Wt[q][kk][h] = W[h][q*H+kk]  (transpose so kernel B reads coalesce)
// ---------------------------------------------------------------------------
__global__ __launch_bounds__(256) void transpose_w(const float* __restrict__ W,
                                                   float* __restrict__ Wt) {
    int g = blockIdx.x * 256 + threadIdx.x;       // 4*H*H = 102400
    if (g >= 4 * H * H) return;
    int h  = g % H;
    int kk = (g / H) % H;
    int q  = g / (H * H);
    Wt[g] = W[h * (4 * H) + q * H + kk];          // write coalesced over h
}

// ---------------------------------------------------------------------------
// Kernel B: Y[q][t][h] = sum_kk pe_q[t][kk] * Wt[q][kk][h]  (+ b[h] folded
// into q==0 table). Each thread computes 4 consecutive t for one (q,h) to
// amortize the Wt read (Wt chunk per q = 102 KB, L2-resident).
// ---------------------------------------------------------------------------
#define TG 257   // ceil(1025/4)

__global__ __launch_bounds__(256) void compute_y(
        const float* __restrict__ pe0, const float* __restrict__ pe1,
        const float* __restrict__ pe2, const float* __restrict__ pe3,
        const float* __restrict__ Wt,  const float* __restrict__ bias,
        float* __restrict__ Y) {
    int e = blockIdx.x * 256 + threadIdx.x;       // over (q, tg, h)
    if (e >= 4 * TG * H) return;
    int h  = e % H;
    int tg = (e / H) % TG;
    int q  = e / (H * TG);
    const float* pe = (q == 0) ? pe0 : (q == 1) ? pe1 : (q == 2) ? pe2 : pe3;

    int t0 = tg * 4;
    int t1 = min(t0 + 1, T_ROWS - 1);             // clamp reads; stores guarded
    int t2 = min(t0 + 2, T_ROWS - 1);
    int t3 = min(t0 + 3, T_ROWS - 1);
    const float* p0 = pe + (size_t)t0 * H;
    const float* p1 = pe + (size_t)t1 * H;
    const float* p2 = pe + (size_t)t2 * H;
    const float* p3 = pe + (size_t)t3 * H;
    const float* wt = Wt + (size_t)q * H * H + h; // stride H over kk, coalesced in h

    float a0 = 0.f, a1 = 0.f, a2 = 0.f, a3 = 0.f;
#pragma unroll 8
    for (int kk = 0; kk < H; ++kk) {
        float w = wt[(size_t)kk * H];
        a0 = fmaf(p0[kk], w, a0);
        a1 = fmaf(p1[kk], w, a1);
        a2 = fmaf(p2[kk], w, a2);
        a3 = fmaf(p3[kk], w, a3);
    }
    float bb = (q == 0) ? bias[h] : 0.f;
    float* yq = Y + ((size_t)q * T_ROWS + t0) * H + h;
    yq[0] = a0 + bb;
    if (t0 + 1 < T_ROWS) yq[H]     = a1 + bb;
    if (t0 + 2 < T_ROWS) yq[2 * H] = a2 + bb;
    if (t0 + 3 < T_ROWS) yq[3 * H] = a3 + bb;
}

// ---------------------------------------------------------------------------
// Kernel C: out[b,i,j,h] = ReLU(Y0[d_ss]+Y1[d_se]+Y2[d_es]+Y3[d_ee])[h]
// One block per (b,i) row; pos rows in LDS; float4 lanes over (j, h/4).
// ---------------------------------------------------------------------------
__global__ __launch_bounds__(256) void gather_add(
        const int* __restrict__ pos_s, const int* __restrict__ pos_e,
        const float* __restrict__ Y, float* __restrict__ out) {
    int bi = blockIdx.x;              // 0..B*S-1
    int bb = bi / S;
    int i  = bi % S;
    int tid = threadIdx.x;

    __shared__ int ls[S], le[S];
    ls[tid] = pos_s[bb * S + tid];
    le[tid] = pos_e[bb * S + tid];
    __syncthreads();

    int psi = ls[i];
    int pei = le[i];

    const float4* __restrict__ Y4 = (const float4*)Y;
    float4* __restrict__ out4 = (float4*)out + (size_t)bi * S * HV;

    // S*HV = 10240 float4 elements per row; 40 iterations of 256 threads
#pragma unroll 4
    for (int base = tid; base < S * HV; base += 256) {
        int j  = base / HV;           // const divide -> magic mul
        int hv = base - j * HV;
        int pj_s = ls[j], pj_e = le[j];
        int d0 = psi - pj_s + MAX_SEP;
        int d1 = psi - pj_e + MAX_SEP;
        int d2 = pei - pj_s + MAX_SEP;
        int d3 = pei - pj_e + MAX_SEP;
        float4 v0 = Y4[(size_t)(0 * T_ROWS + d0) * HV + hv];
        float4 v1 = Y4[(size_t)(1 * T_ROWS + d1) * HV + hv];
        float4 v2 = Y4[(size_t)(2 * T_ROWS + d2) * HV + hv];
        float4 v3 = Y4[(size_t)(3 * T_ROWS + d3) * HV + hv];
        float4 r;
        r.x = fmaxf(v0.x + v1.x + v2.x + v3.x, 0.f);
        r.y = fmaxf(v0.y + v1.y + v2.y + v3.y, 0.f);
        r.z = fmaxf(v0.z + v1.z + v2.z + v3.z, 0.f);
        r.w = fmaxf(v0.w + v1.w + v2.w + v3.w, 0.f);
        out4[base] = r;               // fully coalesced
    }
}

// ---------------------------------------------------------------------------
extern "C" void kernel_launch(void* const* d_in, const int* in_sizes, int n_in,
                              void* d_out, int out_size, void* d_ws, size_t ws_size,
                              hipStream_t stream) {
    const int*   pos_s = (const int*)d_in[0];
    const int*   pos_e = (const int*)d_in[1];
    const float* pe_ss = (const float*)d_in[2];
    const float* pe_se = (const float*)d_in[3];
    const float* pe_es = (const float*)d_in[4];
    const float* pe_ee = (const float*)d_in[5];
    const float* W     = (const float*)d_in[6];
    const float* bias  = (const float*)d_in[7];
    float* out = (float*)d_out;

    // workspace: Wt [4*H*H] then Y [4*T_ROWS*H]
    float* Wt = (float*)d_ws;                       // 409,600 B
    float* Y  = Wt + 4 * H * H;                     // 2,624,000 B

    transpose_w<<<(4 * H * H + 255) / 256, 256, 0, stream>>>(W, Wt);
    compute_y<<<(4 * TG * H + 255) / 256, 256, 0, stream>>>(
        pe_ss, pe_se, pe_es, pe_ee, Wt, bias, Y);
    gather_add<<<B * S, 256, 0, stream>>>(pos_s, pos_e, Y, out);
}